// Round 1
// baseline (1009.591 us; speedup 1.0000x reference)
//
#include <hip/hip_runtime.h>

#define NN 50000
#define NE 800000
#define FD 64
#define PD 20
#define NG 500

// ---------------- setup kernels ----------------

__global__ void k_deg(const int* __restrict__ dst, int* __restrict__ deg) {
    int e = blockIdx.x * 256 + threadIdx.x;
    if (e < NE) atomicAdd(&deg[dst[e]], 1);
}

__global__ void k_dinv(const int* __restrict__ deg, float* __restrict__ dinv) {
    int i = blockIdx.x * 256 + threadIdx.x;
    if (i < NN) dinv[i] = rsqrtf((float)deg[i] + 1.0f);
}

// inclusive scan of deg within 256-blocks; rowp[idx+1] = partial inclusive, bsum[b] = block total
__global__ void k_scan1(const int* __restrict__ deg, int* __restrict__ rowp, int* __restrict__ bsum) {
    __shared__ int lds[256];
    int t = threadIdx.x;
    int idx = blockIdx.x * 256 + t;
    int v = (idx < NN) ? deg[idx] : 0;
    lds[t] = v;
    __syncthreads();
    for (int off = 1; off < 256; off <<= 1) {
        int add = (t >= off) ? lds[t - off] : 0;
        __syncthreads();
        lds[t] += add;
        __syncthreads();
    }
    if (idx < NN) rowp[idx + 1] = lds[t];
    if (t == 255) bsum[blockIdx.x] = lds[255];
}

__global__ void k_scan2(int* bsum, int nB) {
    __shared__ int lds[256];
    int t = threadIdx.x;
    lds[t] = (t < nB) ? bsum[t] : 0;
    __syncthreads();
    for (int off = 1; off < 256; off <<= 1) {
        int add = (t >= off) ? lds[t - off] : 0;
        __syncthreads();
        lds[t] += add;
        __syncthreads();
    }
    if (t < nB) bsum[t] = lds[t];
}

__global__ void k_scan3(int* __restrict__ rowp, const int* __restrict__ bsum) {
    int idx = blockIdx.x * 256 + threadIdx.x;
    if (idx == 0) rowp[0] = 0;
    if (blockIdx.x > 0 && idx < NN) rowp[idx + 1] += bsum[blockIdx.x - 1];
}

__global__ void k_fill_init(const int* __restrict__ rowp, int* __restrict__ fill) {
    int i = blockIdx.x * 256 + threadIdx.x;
    if (i < NN) fill[i] = rowp[i];
}

__global__ void k_csr_fill(const int* __restrict__ srcA, const int* __restrict__ dstA,
                           const float* __restrict__ dinv,
                           int* __restrict__ fill, int* __restrict__ col, float* __restrict__ wgt) {
    int e = blockIdx.x * 256 + threadIdx.x;
    if (e < NE) {
        int s = srcA[e], d = dstA[e];
        int pos = atomicAdd(&fill[d], 1);
        col[pos] = s;
        wgt[pos] = dinv[s] * dinv[d];
    }
}

// ---------------- compute kernels ----------------

// pe = RWPE @ W_rw + b_rw ; h = x + pe   (4 nodes per 256-block)
__global__ void k_pe(const float* __restrict__ x, const float* __restrict__ rwpe,
                     const float* __restrict__ Wrw, const float* __restrict__ brw,
                     float* __restrict__ pe, float* __restrict__ h) {
    __shared__ float Wl[PD * FD];
    __shared__ float rows[4 * PD];
    int t = threadIdx.x;
    int nodeBase = blockIdx.x * 4;
    for (int i = t; i < PD * FD; i += 256) Wl[i] = Wrw[i];
    if (t < 4 * PD) {
        int n = nodeBase + t / PD;
        rows[t] = (n < NN) ? rwpe[n * PD + (t % PD)] : 0.f;
    }
    __syncthreads();
    int f = t & 63, sl = t >> 6;
    int node = nodeBase + sl;
    if (node < NN) {
        float acc = brw[f];
        #pragma unroll
        for (int k = 0; k < PD; k++) acc += rows[sl * PD + k] * Wl[k * FD + f];
        pe[node * FD + f] = acc;
        h[node * FD + f] = x[node * FD + f] + acc;
    }
}

// out[node] = (in [+ in2]) @ W   — 32 nodes per block, 8 per wave-slot
template <bool ADD>
__global__ void k_mm(const float* __restrict__ in, const float* __restrict__ in2,
                     const float* __restrict__ W, float* __restrict__ out) {
    __shared__ float rows[32 * 64];
    int t = threadIdx.x;
    int base = blockIdx.x * 32;
    for (int i = t; i < 32 * 64; i += 256) {
        int node = base + (i >> 6);
        float v = 0.f;
        if (node < NN) {
            v = in[node * 64 + (i & 63)];
            if (ADD) v += in2[node * 64 + (i & 63)];
        }
        rows[i] = v;
    }
    __syncthreads();
    int f = t & 63, w = t >> 6;
    float acc[8] = {0, 0, 0, 0, 0, 0, 0, 0};
    for (int k = 0; k < 64; k++) {
        float wk = W[k * 64 + f];
        #pragma unroll
        for (int n = 0; n < 8; n++) acc[n] += rows[(w * 8 + n) * 64 + k] * wk;
    }
    #pragma unroll
    for (int n = 0; n < 8; n++) {
        int node = base + w * 8 + n;
        if (node < NN) out[node * 64 + f] = acc[n];
    }
}

// gather aggregation: out[i] = sum_e wgt[e]*tin[col[e]] + tin[i]*dinv[i]^2 + b  (+relu)
template <bool RELU>
__global__ void k_agg(const float* __restrict__ tin, const float* __restrict__ bias,
                      const float* __restrict__ dinv,
                      const int* __restrict__ rowp, const int* __restrict__ col,
                      const float* __restrict__ wgt, float* __restrict__ out) {
    int t = threadIdx.x;
    int f = t & 63, sl = t >> 6;
    int node = blockIdx.x * 4 + sl;
    if (node >= NN) return;
    float di = dinv[node];
    float acc = tin[node * 64 + f] * di * di;
    int e0 = rowp[node], e1 = rowp[node + 1];
    for (int e = e0; e < e1; e++) {
        int s = col[e];
        float wv = wgt[e];
        acc += wv * tin[s * 64 + f];
    }
    acc += bias[f];
    if (RELU) acc = fmaxf(acc, 0.f);
    out[node * 64 + f] = acc;
}

// ---------------- batchnorm + pool ----------------

__global__ void k_bnstats(const float* __restrict__ h, float* __restrict__ stats) {
    __shared__ float s1[256], s2[256];
    int t = threadIdx.x;
    int f = t & 63, sl = t >> 6;
    float a = 0.f, b = 0.f;
    for (int node = blockIdx.x * 4 + sl; node < NN; node += gridDim.x * 4) {
        float v = h[node * 64 + f];
        a += v;
        b += v * v;
    }
    s1[t] = a;
    s2[t] = b;
    __syncthreads();
    if (t < 64) {
        a = s1[t] + s1[t + 64] + s1[t + 128] + s1[t + 192];
        b = s2[t] + s2[t + 64] + s2[t + 128] + s2[t + 192];
        atomicAdd(&stats[t], a);
        atomicAdd(&stats[64 + t], b);
    }
}

__global__ void k_bnfinal(float* stats) {
    int f = threadIdx.x;
    if (f < 64) {
        float mu = stats[f] / (float)NN;
        float var = stats[64 + f] / (float)NN - mu * mu;
        stats[f] = mu;
        stats[64 + f] = rsqrtf(var + 1e-5f);
    }
}

__global__ void k_pool(const float* __restrict__ h, const float* __restrict__ stats,
                       const float* __restrict__ gamma, const float* __restrict__ beta,
                       const int* __restrict__ ptr, float* __restrict__ out) {
    int g = blockIdx.x;
    int f = threadIdx.x;
    int s = ptr[g], e = ptr[g + 1];
    float mu = stats[f], rstd = stats[64 + f], ga = gamma[f], be = beta[f];
    float acc = 0.f;
    for (int n = s; n < e; n++) {
        float v = (h[n * 64 + f] - mu) * rstd * ga + be;
        acc += fmaxf(v, 0.f);
    }
    out[g * 64 + f] = acc / (float)(e - s);
}

// ---------------- launch ----------------

extern "C" void kernel_launch(void* const* d_in, const int* in_sizes, int n_in,
                              void* d_out, int out_size, void* d_ws, size_t ws_size,
                              hipStream_t stream) {
    const float* x    = (const float*)d_in[0];
    const float* rwpe = (const float*)d_in[1];
    const float* Wrw  = (const float*)d_in[2];
    const float* brw  = (const float*)d_in[3];
    const float *Wc[5], *bc[5], *Wp[5], *bp[5];
    for (int i = 0; i < 5; i++) {
        Wc[i] = (const float*)d_in[4 + 4 * i];
        bc[i] = (const float*)d_in[5 + 4 * i];
        Wp[i] = (const float*)d_in[6 + 4 * i];
        bp[i] = (const float*)d_in[7 + 4 * i];
    }
    const float* gamma = (const float*)d_in[24];
    const float* beta  = (const float*)d_in[25];
    const int* ei  = (const int*)d_in[26];
    const int* ptr = (const int*)d_in[27];
    float* out = (float*)d_out;

    // workspace layout (256B aligned)
    char* wsp = (char*)d_ws;
    auto alloc = [&](size_t bytes) { void* p = (void*)wsp; wsp += ((bytes + 255) / 256) * 256; return p; };
    int*   deg   = (int*)alloc(NN * 4);
    int*   rowp  = (int*)alloc((NN + 1) * 4);
    int*   fill  = (int*)alloc(NN * 4);
    int*   col   = (int*)alloc(NE * 4);
    float* wgt   = (float*)alloc(NE * 4);
    float* dinv  = (float*)alloc(NN * 4);
    float* pe    = (float*)alloc((size_t)NN * 64 * 4);
    float* h     = (float*)alloc((size_t)NN * 64 * 4);
    float* tb    = (float*)alloc((size_t)NN * 64 * 4);
    float* stats = (float*)alloc(512);
    int*   bsum  = (int*)alloc(256 * 4);

    hipMemsetAsync(deg, 0, NN * 4, stream);
    hipMemsetAsync(stats, 0, 512, stream);

    const int* srcA = ei;
    const int* dstA = ei + NE;

    dim3 b256(256);
    int gE = (NE + 255) / 256;
    int gN = (NN + 255) / 256;       // 196 blocks (<= 256, fits scan2)
    int gNode4 = (NN + 3) / 4;       // 12500
    int gMM = (NN + 31) / 32;        // 1563

    k_deg<<<gE, b256, 0, stream>>>(dstA, deg);
    k_dinv<<<gN, b256, 0, stream>>>(deg, dinv);
    k_scan1<<<gN, b256, 0, stream>>>(deg, rowp, bsum);
    k_scan2<<<1, b256, 0, stream>>>(bsum, gN);
    k_scan3<<<gN, b256, 0, stream>>>(rowp, bsum);
    k_fill_init<<<gN, b256, 0, stream>>>(rowp, fill);
    k_csr_fill<<<gE, b256, 0, stream>>>(srcA, dstA, dinv, fill, col, wgt);

    k_pe<<<gNode4, b256, 0, stream>>>(x, rwpe, Wrw, brw, pe, h);

    // conv1: h = relu(gcn(h, Wc1))
    k_mm<false><<<gMM, b256, 0, stream>>>(h, nullptr, Wc[0], tb);
    k_agg<true><<<gNode4, b256, 0, stream>>>(tb, bc[0], dinv, rowp, col, wgt, h);

    for (int it = 0; it < 4; ++it) {
        // pe = relu(gcn(pe, Wp[it]))
        k_mm<false><<<gMM, b256, 0, stream>>>(pe, nullptr, Wp[it], tb);
        k_agg<true><<<gNode4, b256, 0, stream>>>(tb, bp[it], dinv, rowp, col, wgt, pe);
        // h = gcn(h + pe, Wc[it+1]) (+relu except last)
        k_mm<true><<<gMM, b256, 0, stream>>>(h, pe, Wc[it + 1], tb);
        if (it < 3)
            k_agg<true><<<gNode4, b256, 0, stream>>>(tb, bc[it + 1], dinv, rowp, col, wgt, h);
        else
            k_agg<false><<<gNode4, b256, 0, stream>>>(tb, bc[it + 1], dinv, rowp, col, wgt, h);
    }

    k_bnstats<<<256, b256, 0, stream>>>(h, stats);
    k_bnfinal<<<1, 64, 0, stream>>>(stats);
    k_pool<<<NG, 64, 0, stream>>>(h, stats, gamma, beta, ptr, out);
}

// Round 2
// 592.263 us; speedup vs baseline: 1.7046x; 1.7046x over previous
//
#include <hip/hip_runtime.h>

#define NN 50000
#define NE 800000
#define FD 64
#define PD 20
#define NG 500

// ---------------- setup kernels ----------------

__global__ void k_deg(const int* __restrict__ dst, int* __restrict__ deg) {
    int e = blockIdx.x * 256 + threadIdx.x;
    if (e < NE) atomicAdd(&deg[dst[e]], 1);
}

__global__ void k_dinv(const int* __restrict__ deg, float* __restrict__ dinv) {
    int i = blockIdx.x * 256 + threadIdx.x;
    if (i < NN) dinv[i] = rsqrtf((float)deg[i] + 1.0f);
}

// inclusive scan of deg within 256-blocks; rowp[idx+1] = partial inclusive, bsum[b] = block total
__global__ void k_scan1(const int* __restrict__ deg, int* __restrict__ rowp, int* __restrict__ bsum) {
    __shared__ int lds[256];
    int t = threadIdx.x;
    int idx = blockIdx.x * 256 + t;
    int v = (idx < NN) ? deg[idx] : 0;
    lds[t] = v;
    __syncthreads();
    for (int off = 1; off < 256; off <<= 1) {
        int add = (t >= off) ? lds[t - off] : 0;
        __syncthreads();
        lds[t] += add;
        __syncthreads();
    }
    if (idx < NN) rowp[idx + 1] = lds[t];
    if (t == 255) bsum[blockIdx.x] = lds[255];
}

__global__ void k_scan2(int* bsum, int nB) {
    __shared__ int lds[256];
    int t = threadIdx.x;
    lds[t] = (t < nB) ? bsum[t] : 0;
    __syncthreads();
    for (int off = 1; off < 256; off <<= 1) {
        int add = (t >= off) ? lds[t - off] : 0;
        __syncthreads();
        lds[t] += add;
        __syncthreads();
    }
    if (t < nB) bsum[t] = lds[t];
}

__global__ void k_scan3(int* __restrict__ rowp, const int* __restrict__ bsum) {
    int idx = blockIdx.x * 256 + threadIdx.x;
    if (idx == 0) rowp[0] = 0;
    if (blockIdx.x > 0 && idx < NN) rowp[idx + 1] += bsum[blockIdx.x - 1];
}

__global__ void k_fill_init(const int* __restrict__ rowp, int* __restrict__ fill) {
    int i = blockIdx.x * 256 + threadIdx.x;
    if (i < NN) fill[i] = rowp[i];
}

// meta[pos] = {src, bits(dinv[src])} ; dinv[dst] is factored out and applied in k_agg
__global__ void k_csr_fill(const int* __restrict__ srcA, const int* __restrict__ dstA,
                           const float* __restrict__ dinv,
                           int* __restrict__ fill, int2* __restrict__ meta) {
    int e = blockIdx.x * 256 + threadIdx.x;
    if (e < NE) {
        int s = srcA[e], d = dstA[e];
        int pos = atomicAdd(&fill[d], 1);
        int2 m;
        m.x = s;
        m.y = __float_as_int(dinv[s]);
        meta[pos] = m;
    }
}

// ---------------- compute kernels ----------------

// pe = RWPE @ W_rw + b_rw ; h = x + pe   (4 nodes per 256-block)
__global__ void k_pe(const float* __restrict__ x, const float* __restrict__ rwpe,
                     const float* __restrict__ Wrw, const float* __restrict__ brw,
                     float* __restrict__ pe, float* __restrict__ h) {
    __shared__ float Wl[PD * FD];
    __shared__ float rows[4 * PD];
    int t = threadIdx.x;
    int nodeBase = blockIdx.x * 4;
    for (int i = t; i < PD * FD; i += 256) Wl[i] = Wrw[i];
    if (t < 4 * PD) {
        int n = nodeBase + t / PD;
        rows[t] = (n < NN) ? rwpe[n * PD + (t % PD)] : 0.f;
    }
    __syncthreads();
    int f = t & 63, sl = t >> 6;
    int node = nodeBase + sl;
    if (node < NN) {
        float acc = brw[f];
        #pragma unroll
        for (int k = 0; k < PD; k++) acc += rows[sl * PD + k] * Wl[k * FD + f];
        pe[node * FD + f] = acc;
        h[node * FD + f] = x[node * FD + f] + acc;
    }
}

// out[node] = (in [+ in2]) @ W   — 32 nodes per block, 8 per wave-slot
template <bool ADD>
__global__ void k_mm(const float* __restrict__ in, const float* __restrict__ in2,
                     const float* __restrict__ W, float* __restrict__ out) {
    __shared__ float rows[32 * 64];
    int t = threadIdx.x;
    int base = blockIdx.x * 32;
    // stage 32 rows with float4 loads: 512 float4s, 2 per thread
    for (int i = t; i < 32 * 16; i += 256) {
        int node = base + (i >> 4);
        float4 v = make_float4(0.f, 0.f, 0.f, 0.f);
        if (node < NN) {
            v = *reinterpret_cast<const float4*>(in + (size_t)node * 64 + (i & 15) * 4);
            if (ADD) {
                float4 u = *reinterpret_cast<const float4*>(in2 + (size_t)node * 64 + (i & 15) * 4);
                v.x += u.x; v.y += u.y; v.z += u.z; v.w += u.w;
            }
        }
        *reinterpret_cast<float4*>(&rows[i * 4]) = v;
    }
    __syncthreads();
    int f = t & 63, w = t >> 6;
    float acc[8] = {0, 0, 0, 0, 0, 0, 0, 0};
    for (int k = 0; k < 64; k++) {
        float wk = W[k * 64 + f];
        #pragma unroll
        for (int n = 0; n < 8; n++) acc[n] += rows[(w * 8 + n) * 64 + k] * wk;
    }
    #pragma unroll
    for (int n = 0; n < 8; n++) {
        int node = base + w * 8 + n;
        if (node < NN) out[node * 64 + f] = acc[n];
    }
}

// gather aggregation: out[i] = dinv[i] * sum_e dinv[s_e]*tin[s_e] + tin[i]*dinv[i]^2 + b  (+relu)
// 16 nodes per 256-block, 16 lanes x float4 per node row
template <bool RELU>
__global__ void k_agg(const float* __restrict__ tin, const float* __restrict__ bias,
                      const float* __restrict__ dinv,
                      const int* __restrict__ rowp, const int2* __restrict__ meta,
                      float* __restrict__ out) {
    int t = threadIdx.x;
    int l = t & 15;           // float4 chunk within row
    int sl = t >> 4;          // node slot 0..15
    int node = blockIdx.x * 16 + sl;
    if (node >= NN) return;

    float4 acc = make_float4(0.f, 0.f, 0.f, 0.f);
    int e0 = rowp[node], e1 = rowp[node + 1];
    int e = e0;
    for (; e + 4 <= e1; e += 4) {
        int2 m0 = meta[e + 0];
        int2 m1 = meta[e + 1];
        int2 m2 = meta[e + 2];
        int2 m3 = meta[e + 3];
        float4 r0 = *reinterpret_cast<const float4*>(tin + (size_t)m0.x * 64 + l * 4);
        float4 r1 = *reinterpret_cast<const float4*>(tin + (size_t)m1.x * 64 + l * 4);
        float4 r2 = *reinterpret_cast<const float4*>(tin + (size_t)m2.x * 64 + l * 4);
        float4 r3 = *reinterpret_cast<const float4*>(tin + (size_t)m3.x * 64 + l * 4);
        float w0 = __int_as_float(m0.y), w1 = __int_as_float(m1.y);
        float w2 = __int_as_float(m2.y), w3 = __int_as_float(m3.y);
        acc.x += w0 * r0.x; acc.y += w0 * r0.y; acc.z += w0 * r0.z; acc.w += w0 * r0.w;
        acc.x += w1 * r1.x; acc.y += w1 * r1.y; acc.z += w1 * r1.z; acc.w += w1 * r1.w;
        acc.x += w2 * r2.x; acc.y += w2 * r2.y; acc.z += w2 * r2.z; acc.w += w2 * r2.w;
        acc.x += w3 * r3.x; acc.y += w3 * r3.y; acc.z += w3 * r3.z; acc.w += w3 * r3.w;
    }
    for (; e < e1; ++e) {
        int2 m = meta[e];
        float4 r = *reinterpret_cast<const float4*>(tin + (size_t)m.x * 64 + l * 4);
        float w = __int_as_float(m.y);
        acc.x += w * r.x; acc.y += w * r.y; acc.z += w * r.z; acc.w += w * r.w;
    }

    float dd = dinv[node];
    float4 self = *reinterpret_cast<const float4*>(tin + (size_t)node * 64 + l * 4);
    float4 b = *reinterpret_cast<const float4*>(bias + l * 4);
    float4 o;
    o.x = dd * acc.x + dd * dd * self.x + b.x;
    o.y = dd * acc.y + dd * dd * self.y + b.y;
    o.z = dd * acc.z + dd * dd * self.z + b.z;
    o.w = dd * acc.w + dd * dd * self.w + b.w;
    if (RELU) {
        o.x = fmaxf(o.x, 0.f); o.y = fmaxf(o.y, 0.f);
        o.z = fmaxf(o.z, 0.f); o.w = fmaxf(o.w, 0.f);
    }
    *reinterpret_cast<float4*>(out + (size_t)node * 64 + l * 4) = o;
}

// ---------------- batchnorm + pool ----------------

__global__ void k_bnstats(const float* __restrict__ h, float* __restrict__ stats) {
    __shared__ float s1[256], s2[256];
    int t = threadIdx.x;
    int f = t & 63, sl = t >> 6;
    float a = 0.f, b = 0.f;
    for (int node = blockIdx.x * 4 + sl; node < NN; node += gridDim.x * 4) {
        float v = h[node * 64 + f];
        a += v;
        b += v * v;
    }
    s1[t] = a;
    s2[t] = b;
    __syncthreads();
    if (t < 64) {
        a = s1[t] + s1[t + 64] + s1[t + 128] + s1[t + 192];
        b = s2[t] + s2[t + 64] + s2[t + 128] + s2[t + 192];
        atomicAdd(&stats[t], a);
        atomicAdd(&stats[64 + t], b);
    }
}

__global__ void k_bnfinal(float* stats) {
    int f = threadIdx.x;
    if (f < 64) {
        float mu = stats[f] / (float)NN;
        float var = stats[64 + f] / (float)NN - mu * mu;
        stats[f] = mu;
        stats[64 + f] = rsqrtf(var + 1e-5f);
    }
}

__global__ void k_pool(const float* __restrict__ h, const float* __restrict__ stats,
                       const float* __restrict__ gamma, const float* __restrict__ beta,
                       const int* __restrict__ ptr, float* __restrict__ out) {
    int g = blockIdx.x;
    int f = threadIdx.x;
    int s = ptr[g], e = ptr[g + 1];
    float mu = stats[f], rstd = stats[64 + f], ga = gamma[f], be = beta[f];
    float acc = 0.f;
    for (int n = s; n < e; n++) {
        float v = (h[n * 64 + f] - mu) * rstd * ga + be;
        acc += fmaxf(v, 0.f);
    }
    out[g * 64 + f] = acc / (float)(e - s);
}

// ---------------- launch ----------------

extern "C" void kernel_launch(void* const* d_in, const int* in_sizes, int n_in,
                              void* d_out, int out_size, void* d_ws, size_t ws_size,
                              hipStream_t stream) {
    const float* x    = (const float*)d_in[0];
    const float* rwpe = (const float*)d_in[1];
    const float* Wrw  = (const float*)d_in[2];
    const float* brw  = (const float*)d_in[3];
    const float *Wc[5], *bc[5], *Wp[5], *bp[5];
    for (int i = 0; i < 5; i++) {
        Wc[i] = (const float*)d_in[4 + 4 * i];
        bc[i] = (const float*)d_in[5 + 4 * i];
        Wp[i] = (const float*)d_in[6 + 4 * i];
        bp[i] = (const float*)d_in[7 + 4 * i];
    }
    const float* gamma = (const float*)d_in[24];
    const float* beta  = (const float*)d_in[25];
    const int* ei  = (const int*)d_in[26];
    const int* ptr = (const int*)d_in[27];
    float* out = (float*)d_out;

    // workspace layout (256B aligned)
    char* wsp = (char*)d_ws;
    auto alloc = [&](size_t bytes) { void* p = (void*)wsp; wsp += ((bytes + 255) / 256) * 256; return p; };
    int*   deg   = (int*)alloc(NN * 4);
    int*   rowp  = (int*)alloc((NN + 1) * 4);
    int*   fill  = (int*)alloc(NN * 4);
    int2*  meta  = (int2*)alloc((size_t)NE * 8);
    float* dinv  = (float*)alloc(NN * 4);
    float* pe    = (float*)alloc((size_t)NN * 64 * 4);
    float* h     = (float*)alloc((size_t)NN * 64 * 4);
    float* tb    = (float*)alloc((size_t)NN * 64 * 4);
    float* stats = (float*)alloc(512);
    int*   bsum  = (int*)alloc(256 * 4);

    hipMemsetAsync(deg, 0, NN * 4, stream);
    hipMemsetAsync(stats, 0, 512, stream);

    const int* srcA = ei;
    const int* dstA = ei + NE;

    dim3 b256(256);
    int gE = (NE + 255) / 256;
    int gN = (NN + 255) / 256;       // 196 blocks (<= 256, fits scan2)
    int gNode16 = (NN + 15) / 16;    // 3125
    int gMM = (NN + 31) / 32;        // 1563

    k_deg<<<gE, b256, 0, stream>>>(dstA, deg);
    k_dinv<<<gN, b256, 0, stream>>>(deg, dinv);
    k_scan1<<<gN, b256, 0, stream>>>(deg, rowp, bsum);
    k_scan2<<<1, b256, 0, stream>>>(bsum, gN);
    k_scan3<<<gN, b256, 0, stream>>>(rowp, bsum);
    k_fill_init<<<gN, b256, 0, stream>>>(rowp, fill);
    k_csr_fill<<<gE, b256, 0, stream>>>(srcA, dstA, dinv, fill, meta);

    k_pe<<<(NN + 3) / 4, b256, 0, stream>>>(x, rwpe, Wrw, brw, pe, h);

    // conv1: h = relu(gcn(h, Wc1))
    k_mm<false><<<gMM, b256, 0, stream>>>(h, nullptr, Wc[0], tb);
    k_agg<true><<<gNode16, b256, 0, stream>>>(tb, bc[0], dinv, rowp, meta, h);

    for (int it = 0; it < 4; ++it) {
        // pe = relu(gcn(pe, Wp[it]))
        k_mm<false><<<gMM, b256, 0, stream>>>(pe, nullptr, Wp[it], tb);
        k_agg<true><<<gNode16, b256, 0, stream>>>(tb, bp[it], dinv, rowp, meta, pe);
        // h = gcn(h + pe, Wc[it+1]) (+relu except last)
        k_mm<true><<<gMM, b256, 0, stream>>>(h, pe, Wc[it + 1], tb);
        if (it < 3)
            k_agg<true><<<gNode16, b256, 0, stream>>>(tb, bc[it + 1], dinv, rowp, meta, h);
        else
            k_agg<false><<<gNode16, b256, 0, stream>>>(tb, bc[it + 1], dinv, rowp, meta, h);
    }

    k_bnstats<<<256, b256, 0, stream>>>(h, stats);
    k_bnfinal<<<1, 64, 0, stream>>>(stats);
    k_pool<<<NG, 64, 0, stream>>>(h, stats, gamma, beta, ptr, out);
}

// Round 3
// 493.453 us; speedup vs baseline: 2.0460x; 1.2002x over previous
//
#include <hip/hip_runtime.h>

#define NN 50000
#define NE 800000
#define FD 64
#define PD 20
#define NG 500

// ---------------- setup kernels ----------------

__global__ void k_deg(const int* __restrict__ dst, int* __restrict__ deg) {
    int e = blockIdx.x * 256 + threadIdx.x;
    if (e < NE) atomicAdd(&deg[dst[e]], 1);
}

__global__ void k_dinv(const int* __restrict__ deg, float* __restrict__ dinv) {
    int i = blockIdx.x * 256 + threadIdx.x;
    if (i < NN) dinv[i] = rsqrtf((float)deg[i] + 1.0f);
}

// inclusive scan of deg within 256-blocks; rowp[idx+1] = partial inclusive, bsum[b] = block total
__global__ void k_scan1(const int* __restrict__ deg, int* __restrict__ rowp, int* __restrict__ bsum) {
    __shared__ int lds[256];
    int t = threadIdx.x;
    int idx = blockIdx.x * 256 + t;
    int v = (idx < NN) ? deg[idx] : 0;
    lds[t] = v;
    __syncthreads();
    for (int off = 1; off < 256; off <<= 1) {
        int add = (t >= off) ? lds[t - off] : 0;
        __syncthreads();
        lds[t] += add;
        __syncthreads();
    }
    if (idx < NN) rowp[idx + 1] = lds[t];
    if (t == 255) bsum[blockIdx.x] = lds[255];
}

__global__ void k_scan2(int* bsum, int nB) {
    __shared__ int lds[256];
    int t = threadIdx.x;
    lds[t] = (t < nB) ? bsum[t] : 0;
    __syncthreads();
    for (int off = 1; off < 256; off <<= 1) {
        int add = (t >= off) ? lds[t - off] : 0;
        __syncthreads();
        lds[t] += add;
        __syncthreads();
    }
    if (t < nB) bsum[t] = lds[t];
}

__global__ void k_scan3(int* __restrict__ rowp, const int* __restrict__ bsum) {
    int idx = blockIdx.x * 256 + threadIdx.x;
    if (idx == 0) rowp[0] = 0;
    if (blockIdx.x > 0 && idx < NN) rowp[idx + 1] += bsum[blockIdx.x - 1];
}

__global__ void k_fill_init(const int* __restrict__ rowp, int* __restrict__ fill) {
    int i = blockIdx.x * 256 + threadIdx.x;
    if (i < NN) fill[i] = rowp[i];
}

// meta[pos] = {src, bits(dinv[src])} ; dinv[dst] is factored out and applied in k_aggmm
__global__ void k_csr_fill(const int* __restrict__ srcA, const int* __restrict__ dstA,
                           const float* __restrict__ dinv,
                           int* __restrict__ fill, int2* __restrict__ meta) {
    int e = blockIdx.x * 256 + threadIdx.x;
    if (e < NE) {
        int s = srcA[e], d = dstA[e];
        int pos = atomicAdd(&fill[d], 1);
        int2 m;
        m.x = s;
        m.y = __float_as_int(dinv[s]);
        meta[pos] = m;
    }
}

// ---------------- compute kernels ----------------

// pe = RWPE @ W_rw + b_rw ; h = x + pe   (4 nodes per 256-block)
__global__ void k_pe(const float* __restrict__ x, const float* __restrict__ rwpe,
                     const float* __restrict__ Wrw, const float* __restrict__ brw,
                     float* __restrict__ pe, float* __restrict__ h) {
    __shared__ float Wl[PD * FD];
    __shared__ float rows[4 * PD];
    int t = threadIdx.x;
    int nodeBase = blockIdx.x * 4;
    for (int i = t; i < PD * FD; i += 256) Wl[i] = Wrw[i];
    if (t < 4 * PD) {
        int n = nodeBase + t / PD;
        rows[t] = (n < NN) ? rwpe[n * PD + (t % PD)] : 0.f;
    }
    __syncthreads();
    int f = t & 63, sl = t >> 6;
    int node = nodeBase + sl;
    if (node < NN) {
        float acc = brw[f];
        #pragma unroll
        for (int k = 0; k < PD; k++) acc += rows[sl * PD + k] * Wl[k * FD + f];
        pe[node * FD + f] = acc;
        h[node * FD + f] = x[node * FD + f] + acc;
    }
}

// Fused GCN conv using linearity: out = relu( agg_norm(a) @ W + b )
//   agg_norm(a)[i] = dinv_i * sum_e dinv_{s_e} a[s_e]  +  dinv_i^2 * a[i]
// 16 nodes per 256-block (NN % 16 == 0), 16 lanes x float4 per node row.
// If WRITESUM: also writes sout[node] = hsrc[node] + out[node] (out has relu applied).
template <bool RELU, bool WRITESUM>
__global__ void k_aggmm(const float* __restrict__ a, const float* __restrict__ dinv,
                        const int* __restrict__ rowp, const int2* __restrict__ meta,
                        const float* __restrict__ W, const float* __restrict__ bias,
                        float* __restrict__ out,
                        const float* __restrict__ hsrc, float* __restrict__ sout) {
    __shared__ float aggL[16 * 68];     // 16 rows, padded stride 68
    __shared__ float Wl[64 * 64];       // W staged row-major [k][f]
    int t = threadIdx.x;

    // stage W (1024 float4s, 4 per thread)
    {
        const float4* W4 = reinterpret_cast<const float4*>(W);
        float4* Wl4 = reinterpret_cast<float4*>(Wl);
        #pragma unroll
        for (int i = 0; i < 4; i++) Wl4[t + 256 * i] = W4[t + 256 * i];
    }

    int l = t & 15;           // float4 chunk within row
    int sl = t >> 4;          // node slot 0..15
    int node = blockIdx.x * 16 + sl;

    // phase 1: gather-aggregate
    float4 acc = make_float4(0.f, 0.f, 0.f, 0.f);
    int e0 = rowp[node], e1 = rowp[node + 1];
    int e = e0;
    for (; e + 4 <= e1; e += 4) {
        int2 m0 = meta[e + 0];
        int2 m1 = meta[e + 1];
        int2 m2 = meta[e + 2];
        int2 m3 = meta[e + 3];
        float4 r0 = *reinterpret_cast<const float4*>(a + (size_t)m0.x * 64 + l * 4);
        float4 r1 = *reinterpret_cast<const float4*>(a + (size_t)m1.x * 64 + l * 4);
        float4 r2 = *reinterpret_cast<const float4*>(a + (size_t)m2.x * 64 + l * 4);
        float4 r3 = *reinterpret_cast<const float4*>(a + (size_t)m3.x * 64 + l * 4);
        float w0 = __int_as_float(m0.y), w1 = __int_as_float(m1.y);
        float w2 = __int_as_float(m2.y), w3 = __int_as_float(m3.y);
        acc.x += w0 * r0.x; acc.y += w0 * r0.y; acc.z += w0 * r0.z; acc.w += w0 * r0.w;
        acc.x += w1 * r1.x; acc.y += w1 * r1.y; acc.z += w1 * r1.z; acc.w += w1 * r1.w;
        acc.x += w2 * r2.x; acc.y += w2 * r2.y; acc.z += w2 * r2.z; acc.w += w2 * r2.w;
        acc.x += w3 * r3.x; acc.y += w3 * r3.y; acc.z += w3 * r3.z; acc.w += w3 * r3.w;
    }
    for (; e < e1; ++e) {
        int2 m = meta[e];
        float4 r = *reinterpret_cast<const float4*>(a + (size_t)m.x * 64 + l * 4);
        float w = __int_as_float(m.y);
        acc.x += w * r.x; acc.y += w * r.y; acc.z += w * r.z; acc.w += w * r.w;
    }
    {
        float dd = dinv[node];
        float4 self = *reinterpret_cast<const float4*>(a + (size_t)node * 64 + l * 4);
        float4 v;
        v.x = dd * acc.x + dd * dd * self.x;
        v.y = dd * acc.y + dd * dd * self.y;
        v.z = dd * acc.z + dd * dd * self.z;
        v.w = dd * acc.w + dd * dd * self.w;
        *reinterpret_cast<float4*>(&aggL[sl * 68 + l * 4]) = v;
    }
    __syncthreads();

    // phase 2: out[node] = aggL[node] @ W + b
    int c = t & 15;           // output float4 chunk
    int sl2 = t >> 4;
    int onode = blockIdx.x * 16 + sl2;
    float4 o = *reinterpret_cast<const float4*>(bias + c * 4);
    const float* arow = &aggL[sl2 * 68];
    #pragma unroll 16
    for (int k = 0; k < 64; k++) {
        float av = arow[k];
        float4 wv = *reinterpret_cast<const float4*>(&Wl[k * 64 + c * 4]);
        o.x += av * wv.x; o.y += av * wv.y; o.z += av * wv.z; o.w += av * wv.w;
    }
    if (RELU) {
        o.x = fmaxf(o.x, 0.f); o.y = fmaxf(o.y, 0.f);
        o.z = fmaxf(o.z, 0.f); o.w = fmaxf(o.w, 0.f);
    }
    *reinterpret_cast<float4*>(out + (size_t)onode * 64 + c * 4) = o;
    if (WRITESUM) {
        float4 hv = *reinterpret_cast<const float4*>(hsrc + (size_t)onode * 64 + c * 4);
        float4 sv;
        sv.x = hv.x + o.x; sv.y = hv.y + o.y; sv.z = hv.z + o.z; sv.w = hv.w + o.w;
        *reinterpret_cast<float4*>(sout + (size_t)onode * 64 + c * 4) = sv;
    }
}

// ---------------- batchnorm + pool ----------------

__global__ void k_bnstats(const float* __restrict__ h, float* __restrict__ stats) {
    __shared__ float s1[256], s2[256];
    int t = threadIdx.x;
    int f = t & 63, sl = t >> 6;
    float a = 0.f, b = 0.f;
    for (int node = blockIdx.x * 4 + sl; node < NN; node += gridDim.x * 4) {
        float v = h[node * 64 + f];
        a += v;
        b += v * v;
    }
    s1[t] = a;
    s2[t] = b;
    __syncthreads();
    if (t < 64) {
        a = s1[t] + s1[t + 64] + s1[t + 128] + s1[t + 192];
        b = s2[t] + s2[t + 64] + s2[t + 128] + s2[t + 192];
        atomicAdd(&stats[t], a);
        atomicAdd(&stats[64 + t], b);
    }
}

__global__ void k_bnfinal(float* stats) {
    int f = threadIdx.x;
    if (f < 64) {
        float mu = stats[f] / (float)NN;
        float var = stats[64 + f] / (float)NN - mu * mu;
        stats[f] = mu;
        stats[64 + f] = rsqrtf(var + 1e-5f);
    }
}

__global__ void k_pool(const float* __restrict__ h, const float* __restrict__ stats,
                       const float* __restrict__ gamma, const float* __restrict__ beta,
                       const int* __restrict__ ptr, float* __restrict__ out) {
    int g = blockIdx.x;
    int f = threadIdx.x;
    int s = ptr[g], e = ptr[g + 1];
    float mu = stats[f], rstd = stats[64 + f], ga = gamma[f], be = beta[f];
    float acc = 0.f;
    for (int n = s; n < e; n++) {
        float v = (h[n * 64 + f] - mu) * rstd * ga + be;
        acc += fmaxf(v, 0.f);
    }
    out[g * 64 + f] = acc / (float)(e - s);
}

// ---------------- launch ----------------

extern "C" void kernel_launch(void* const* d_in, const int* in_sizes, int n_in,
                              void* d_out, int out_size, void* d_ws, size_t ws_size,
                              hipStream_t stream) {
    const float* x    = (const float*)d_in[0];
    const float* rwpe = (const float*)d_in[1];
    const float* Wrw  = (const float*)d_in[2];
    const float* brw  = (const float*)d_in[3];
    const float *Wc[5], *bc[5], *Wp[5], *bp[5];
    for (int i = 0; i < 5; i++) {
        Wc[i] = (const float*)d_in[4 + 4 * i];
        bc[i] = (const float*)d_in[5 + 4 * i];
        Wp[i] = (const float*)d_in[6 + 4 * i];
        bp[i] = (const float*)d_in[7 + 4 * i];
    }
    const float* gamma = (const float*)d_in[24];
    const float* beta  = (const float*)d_in[25];
    const int* ei  = (const int*)d_in[26];
    const int* ptr = (const int*)d_in[27];
    float* out = (float*)d_out;

    // workspace layout (256B aligned)
    char* wsp = (char*)d_ws;
    auto alloc = [&](size_t bytes) { void* p = (void*)wsp; wsp += ((bytes + 255) / 256) * 256; return p; };
    int*   deg   = (int*)alloc(NN * 4);
    int*   rowp  = (int*)alloc((NN + 1) * 4);
    int*   fill  = (int*)alloc(NN * 4);
    int2*  meta  = (int2*)alloc((size_t)NE * 8);
    float* dinv  = (float*)alloc(NN * 4);
    float* pe0   = (float*)alloc((size_t)NN * 64 * 4);
    float* pe1   = (float*)alloc((size_t)NN * 64 * 4);
    float* h0    = (float*)alloc((size_t)NN * 64 * 4);   // also used as s-buffer
    float* h1    = (float*)alloc((size_t)NN * 64 * 4);   // h always ends up here
    float* stats = (float*)alloc(512);
    int*   bsum  = (int*)alloc(256 * 4);

    hipMemsetAsync(deg, 0, NN * 4, stream);
    hipMemsetAsync(stats, 0, 512, stream);

    const int* srcA = ei;
    const int* dstA = ei + NE;

    dim3 b256(256);
    int gE = (NE + 255) / 256;
    int gN = (NN + 255) / 256;       // 196 blocks (<= 256, fits scan2)
    int gNode16 = NN / 16;           // 3125 (exact)

    k_deg<<<gE, b256, 0, stream>>>(dstA, deg);
    k_dinv<<<gN, b256, 0, stream>>>(deg, dinv);
    k_scan1<<<gN, b256, 0, stream>>>(deg, rowp, bsum);
    k_scan2<<<1, b256, 0, stream>>>(bsum, gN);
    k_scan3<<<gN, b256, 0, stream>>>(rowp, bsum);
    k_fill_init<<<gN, b256, 0, stream>>>(rowp, fill);
    k_csr_fill<<<gE, b256, 0, stream>>>(srcA, dstA, dinv, fill, meta);

    k_pe<<<(NN + 3) / 4, b256, 0, stream>>>(x, rwpe, Wrw, brw, pe0, h0);

    // conv1: h1 = relu( agg(h0) @ Wc1 + bc1 )
    k_aggmm<true, false><<<gNode16, b256, 0, stream>>>(
        h0, dinv, rowp, meta, Wc[0], bc[0], h1, nullptr, nullptr);

    float* peA = pe0;
    float* peB = pe1;
    for (int it = 0; it < 4; ++it) {
        // peB = relu( agg(peA) @ Wp + bp );  h0 = h1 + peB
        k_aggmm<true, true><<<gNode16, b256, 0, stream>>>(
            peA, dinv, rowp, meta, Wp[it], bp[it], peB, h1, h0);
        // h1 = agg(h0) @ Wc + bc (+relu except last)
        if (it < 3)
            k_aggmm<true, false><<<gNode16, b256, 0, stream>>>(
                h0, dinv, rowp, meta, Wc[it + 1], bc[it + 1], h1, nullptr, nullptr);
        else
            k_aggmm<false, false><<<gNode16, b256, 0, stream>>>(
                h0, dinv, rowp, meta, Wc[it + 1], bc[it + 1], h1, nullptr, nullptr);
        float* tmp = peA; peA = peB; peB = tmp;
    }

    k_bnstats<<<256, b256, 0, stream>>>(h1, stats);
    k_bnfinal<<<1, 64, 0, stream>>>(stats);
    k_pool<<<NG, 64, 0, stream>>>(h1, stats, gamma, beta, ptr, out);
}